// Round 4
// baseline (4065.028 us; speedup 1.0000x reference)
//
#include <hip/hip_runtime.h>
#include <hip/hip_bf16.h>

#define S_LEN 4096
#define D_MODEL 512
#define NHEADS 4
#define HEAD_DIM 128
#define BATCH 2
#define M_ROWS (BATCH * S_LEN) /* 8192 */

typedef __hip_bfloat16 bf16;

__device__ __forceinline__ float bf16_to_f32_raw(unsigned short u) {
    unsigned int x = ((unsigned int)u) << 16;
    return __uint_as_float(x);
}

__device__ __forceinline__ float load_elem(const void* p, long long idx, int f32) {
    if (f32) return ((const float*)p)[idx];
    return bf16_to_f32_raw(((const unsigned short*)p)[idx]);
}

// Per-tensor dtype detection. Reading n uint16s is safe whether the buffer is
// bf16 (whole buffer) or fp32 (first half). Genuine bf16 data has no nonzero
// samples outside [1e-12, 1e12]; fp32 buffers read as uint16 have ~68% of
// low-mantissa halves decoding to NaN/huge/tiny bf16 values.
__global__ __launch_bounds__(256) void detect_kernel(
    const void* a0, const void* a1, const void* a2, const void* a3,
    const void* a4, const void* a5, const void* a6,
    int n0, int n1, int n2, int n3, int n4, int n5, int n6, int* flags) {
    const void* p = a0;
    int n = n0;
    switch (blockIdx.x) {
        case 0: p = a0; n = n0; break;
        case 1: p = a1; n = n1; break;
        case 2: p = a2; n = n2; break;
        case 3: p = a3; n = n3; break;
        case 4: p = a4; n = n4; break;
        case 5: p = a5; n = n5; break;
        case 6: p = a6; n = n6; break;
    }
    __shared__ int s_cnt;
    if (threadIdx.x == 0) s_cnt = 0;
    __syncthreads();
    int samp = n < 4096 ? n : 4096;
    const unsigned short* u = (const unsigned short*)p;
    int cnt = 0;
    for (int i = threadIdx.x; i < samp; i += 256) {
        float f = bf16_to_f32_raw(u[i]);
        float af = fabsf(f);
        if (af != 0.0f && (!(af <= 1e12f) || af < 1e-12f)) cnt++; // NaN counts
    }
    atomicAdd(&s_cnt, cnt);
    __syncthreads();
    if (threadIdx.x == 0) flags[blockIdx.x] = (s_cnt > 16) ? 1 : 0;
}

// C[row,col] = (A[row,:] . W[:,col]) * scale, scattered to q/k/v[b][h][s][hd] bf16.
// One thread per output element; block = one row x 256 cols.
__global__ __launch_bounds__(256) void proj_qkv_simple(const void* A, const void* W,
                                                       bf16* out, float scale,
                                                       const int* flags, int ia, int iw) {
    const int row = blockIdx.x;
    const int col = blockIdx.y * 256 + threadIdx.x;
    const int f32a = flags[ia];
    const int f32w = flags[iw];
    float acc = 0.f;
    for (int k = 0; k < D_MODEL; k++) {
        float a = load_elem(A, (long long)row * D_MODEL + k, f32a);
        float w = load_elem(W, (long long)k * D_MODEL + col, f32w);
        acc += a * w;
    }
    const int b = row >> 12, s = row & (S_LEN - 1);
    const int h = col >> 7, hd = col & 127;
    out[((long long)(b * NHEADS + h) * S_LEN + s) * HEAD_DIM + hd] =
        __float2bfloat16(acc * scale);
}

// One block per (b,h,q_row). Scores for the contiguous allowed key range in LDS,
// block-wide max and sum reductions, then coalesced P.V over d.
__global__ __launch_bounds__(256) void attn_simple(const bf16* q, const bf16* k,
                                                   const bf16* v, bf16* attn) {
    const int bid = blockIdx.x; // 0..32767
    const int bh = bid >> 12;   // b*4 + h
    const int qrow = bid & (S_LEN - 1);
    const int t = threadIdx.x;
    __shared__ float sQ[HEAD_DIM];
    __shared__ float sS[3 * 512];
    __shared__ float red[256];

    const int qblk = qrow >> 9;
    const int kstart = (qblk == 0) ? 0 : ((qblk - 1) << 9);
    const int kend = (qblk == 7) ? S_LEN : ((qblk + 2) << 9);
    const int kcount = kend - kstart;

    if (t < HEAD_DIM)
        sQ[t] = __bfloat162float(q[((size_t)bh * S_LEN + qrow) * HEAD_DIM + t]);
    __syncthreads();

    float lmax = -1e30f;
    for (int kk = t; kk < kcount; kk += 256) {
        const bf16* kp = k + ((size_t)bh * S_LEN + kstart + kk) * HEAD_DIM;
        float sc = 0.f;
        for (int d = 0; d < HEAD_DIM; d++) sc += sQ[d] * __bfloat162float(kp[d]);
        sS[kk] = sc;
        lmax = fmaxf(lmax, sc);
    }
    red[t] = lmax;
    __syncthreads();
    for (int off = 128; off > 0; off >>= 1) {
        if (t < off) red[t] = fmaxf(red[t], red[t + off]);
        __syncthreads();
    }
    const float m = red[0];
    __syncthreads();

    float lsum = 0.f;
    for (int kk = t; kk < kcount; kk += 256) {
        float p = __expf(sS[kk] - m);
        sS[kk] = p;
        lsum += p;
    }
    red[t] = lsum;
    __syncthreads();
    for (int off = 128; off > 0; off >>= 1) {
        if (t < off) red[t] += red[t + off];
        __syncthreads();
    }
    const float inv = 1.0f / red[0];

    if (t < HEAD_DIM) {
        float acc = 0.f;
        const bf16* vp = v + ((size_t)bh * S_LEN + kstart) * HEAD_DIM + t;
        for (int kk = 0; kk < kcount; kk++)
            acc += sS[kk] * __bfloat162float(vp[(size_t)kk * HEAD_DIM]);
        const int b = bh >> 2, h = bh & 3;
        attn[((size_t)(b * S_LEN + qrow)) * D_MODEL + h * HEAD_DIM + t] =
            __float2bfloat16(acc * inv);
    }
}

// out[row,col] = attn[row,:] . Wo[:,col] + bo[col] -> FLOAT32 out (reference dtype).
__global__ __launch_bounds__(256) void out_proj_simple(const bf16* A, const void* W,
                                                       const void* bias, float* out,
                                                       const int* flags) {
    const int row = blockIdx.x;
    const int col = blockIdx.y * 256 + threadIdx.x;
    const int f32w = flags[5];
    const int f32b = flags[6];
    float acc = load_elem(bias, col, f32b);
    for (int kk = 0; kk < D_MODEL; kk++) {
        float a = __bfloat162float(A[(long long)row * D_MODEL + kk]);
        float w = load_elem(W, (long long)kk * D_MODEL + col, f32w);
        acc += a * w;
    }
    out[(long long)row * D_MODEL + col] = acc;
}

extern "C" void kernel_launch(void* const* d_in, const int* in_sizes, int n_in,
                              void* d_out, int out_size, void* d_ws, size_t ws_size,
                              hipStream_t stream) {
    (void)out_size; (void)ws_size; (void)n_in;
    const void* q_input = d_in[0];
    const void* kv_input = d_in[1];
    const void* Wq = d_in[2];
    const void* Wk = d_in[3];
    const void* Wv = d_in[4];
    const void* Wo = d_in[5];
    const void* bo = d_in[6];
    // d_in[7] = mask: tri-block-diagonal, BLK=512, handled analytically.

    int* flags = (int*)d_ws; // offset 0: 7 ints
    const size_t NELEM = (size_t)M_ROWS * D_MODEL; // 4,194,304
    bf16* qb = (bf16*)((char*)d_ws + 256);
    bf16* kb = qb + NELEM;
    bf16* vb = kb + NELEM;
    bf16* attn = vb + NELEM;
    // ws usage: 256 B + 4 * 8 MiB = 32 MiB + 256 B

    detect_kernel<<<7, 256, 0, stream>>>(q_input, kv_input, Wq, Wk, Wv, Wo, bo,
                                         in_sizes[0], in_sizes[1], in_sizes[2],
                                         in_sizes[3], in_sizes[4], in_sizes[5],
                                         in_sizes[6], flags);

    dim3 pgrid(M_ROWS, D_MODEL / 256);
    const float qscale = 0.0883883476483184f; // HD^-0.5
    proj_qkv_simple<<<pgrid, 256, 0, stream>>>(q_input, Wq, qb, qscale, flags, 0, 2);
    proj_qkv_simple<<<pgrid, 256, 0, stream>>>(kv_input, Wk, kb, 1.0f, flags, 1, 3);
    proj_qkv_simple<<<pgrid, 256, 0, stream>>>(kv_input, Wv, vb, 1.0f, flags, 1, 4);

    attn_simple<<<BATCH * NHEADS * S_LEN, 256, 0, stream>>>(qb, kb, vb, attn);

    out_proj_simple<<<pgrid, 256, 0, stream>>>(attn, Wo, bo, (float*)d_out, flags);
}

// Round 5
// 294.770 us; speedup vs baseline: 13.7905x; 13.7905x over previous
//
#include <hip/hip_runtime.h>
#include <hip/hip_bf16.h>

#define S_LEN 4096
#define D_MODEL 512
#define NHEADS 4
#define HEAD_DIM 128
#define BATCH 2
#define M_ROWS 8192

typedef unsigned short u16;
typedef __attribute__((ext_vector_type(8))) short bf16x8;
typedef __attribute__((ext_vector_type(4))) float f32x4;

__device__ __forceinline__ float bf2f(u16 u) {
    return __uint_as_float(((unsigned)u) << 16);
}
__device__ __forceinline__ short f2b(float f) { // RNE f32->bf16
    unsigned x = __float_as_uint(f);
    unsigned r = (x + 0x7fffu + ((x >> 16) & 1u)) >> 16;
    return (short)r;
}
__device__ __forceinline__ float load_elem(const void* p, long long idx, int f32) {
    if (f32) return ((const float*)p)[idx];
    return bf2f(((const u16*)p)[idx]);
}

// ---- per-tensor dtype detection (unchanged from passing round) ----
__global__ __launch_bounds__(256) void detect_kernel(
    const void* a0, const void* a1, const void* a2, const void* a3,
    const void* a4, const void* a5, const void* a6,
    int n0, int n1, int n2, int n3, int n4, int n5, int n6, int* flags) {
    const void* p = a0;
    int n = n0;
    switch (blockIdx.x) {
        case 0: p = a0; n = n0; break;
        case 1: p = a1; n = n1; break;
        case 2: p = a2; n = n2; break;
        case 3: p = a3; n = n3; break;
        case 4: p = a4; n = n4; break;
        case 5: p = a5; n = n5; break;
        case 6: p = a6; n = n6; break;
    }
    __shared__ int s_cnt;
    if (threadIdx.x == 0) s_cnt = 0;
    __syncthreads();
    int samp = n < 4096 ? n : 4096;
    const u16* u = (const u16*)p;
    int cnt = 0;
    for (int i = threadIdx.x; i < samp; i += 256) {
        float f = bf2f(u[i]);
        float af = fabsf(f);
        if (af != 0.0f && (!(af <= 1e12f) || af < 1e-12f)) cnt++;
    }
    atomicAdd(&s_cnt, cnt);
    __syncthreads();
    if (threadIdx.x == 0) flags[blockIdx.x] = (s_cnt > 16) ? 1 : 0;
}

// ---- weights: W[k][n] (f32|bf16) -> Wt[n][k] bf16, 4 matrices ----
__global__ __launch_bounds__(256) void prep_weights(const void* w0, const void* w1,
                                                    const void* w2, const void* w3,
                                                    u16* wt, const int* flags) {
    const void* W;
    int f32;
    switch (blockIdx.z) {
        case 0: W = w0; f32 = flags[2]; break;
        case 1: W = w1; f32 = flags[3]; break;
        case 2: W = w2; f32 = flags[4]; break;
        default: W = w3; f32 = flags[5]; break;
    }
    u16* Wt = wt + (size_t)blockIdx.z * D_MODEL * D_MODEL;
    __shared__ float tile[32][33];
    const int k0 = blockIdx.x * 32, n0 = blockIdx.y * 32;
    const int tx = threadIdx.x & 31, ty = threadIdx.x >> 5;
#pragma unroll
    for (int i = 0; i < 4; i++) {
        int r = ty + 8 * i;
        tile[r][tx] = load_elem(W, (long long)(k0 + r) * D_MODEL + n0 + tx, f32);
    }
    __syncthreads();
#pragma unroll
    for (int i = 0; i < 4; i++) {
        int r = ty + 8 * i;
        Wt[(size_t)(n0 + r) * D_MODEL + k0 + tx] = (u16)f2b(tile[tx][r]);
    }
}

// ---- QKV projection: C = A @ W, MFMA 16x16x32 bf16, 128x128 tile ----
// z=0: q_input@Wq*qscale -> qb[bh][s][d]; z=1: kv@Wk -> kb[bh][s][d];
// z=2: kv@Wv -> vbT[bh][d][s] (transposed for attention PV B-frags).
__global__ __launch_bounds__(256) void proj_mfma(const void* qin, const void* kvin,
                                                 const u16* wt, u16* qb, u16* kb,
                                                 u16* vbT, const int* flags) {
    __shared__ short As[128][40];
    __shared__ short Ws[128][40];
    const int z = blockIdx.z;
    const void* A;
    int f32a;
    const u16* Wt;
    if (z == 0) { A = qin; f32a = flags[0]; Wt = wt; }
    else if (z == 1) { A = kvin; f32a = flags[1]; Wt = wt + 262144; }
    else { A = kvin; f32a = flags[1]; Wt = wt + 2 * 262144; }
    const int row0 = blockIdx.x * 128, col0 = blockIdx.y * 128;
    const int tid = threadIdx.x;
    const int srow = tid >> 1, skh = (tid & 1) << 4;
    const int lane = tid & 63, wid = tid >> 6;
    const int wm = wid >> 1, wn = wid & 1;
    const int l16 = lane & 15, quad = lane >> 4;

    f32x4 acc[4][4];
#pragma unroll
    for (int i = 0; i < 4; i++)
#pragma unroll
        for (int j = 0; j < 4; j++) acc[i][j] = (f32x4){0.f, 0.f, 0.f, 0.f};

    for (int k0 = 0; k0 < D_MODEL; k0 += 32) {
        if (f32a) {
            const float* ap = (const float*)A + (size_t)(row0 + srow) * D_MODEL + k0 + skh;
            short s[16];
#pragma unroll
            for (int i = 0; i < 4; i++) {
                f32x4 t = *(const f32x4*)(ap + 4 * i);
                s[4 * i] = f2b(t.x); s[4 * i + 1] = f2b(t.y);
                s[4 * i + 2] = f2b(t.z); s[4 * i + 3] = f2b(t.w);
            }
            *(bf16x8*)&As[srow][skh] = *(bf16x8*)s;
            *(bf16x8*)&As[srow][skh + 8] = *(bf16x8*)(s + 8);
        } else {
            const u16* ap = (const u16*)A + (size_t)(row0 + srow) * D_MODEL + k0 + skh;
            *(bf16x8*)&As[srow][skh] = *(const bf16x8*)ap;
            *(bf16x8*)&As[srow][skh + 8] = *(const bf16x8*)(ap + 8);
        }
        {
            const u16* wp = Wt + (size_t)(col0 + srow) * D_MODEL + k0 + skh;
            *(bf16x8*)&Ws[srow][skh] = *(const bf16x8*)wp;
            *(bf16x8*)&Ws[srow][skh + 8] = *(const bf16x8*)(wp + 8);
        }
        __syncthreads();
        bf16x8 af[4], bfr[4];
#pragma unroll
        for (int i = 0; i < 4; i++)
            af[i] = *(const bf16x8*)&As[wm * 64 + i * 16 + l16][quad * 8];
#pragma unroll
        for (int j = 0; j < 4; j++)
            bfr[j] = *(const bf16x8*)&Ws[wn * 64 + j * 16 + l16][quad * 8];
#pragma unroll
        for (int i = 0; i < 4; i++)
#pragma unroll
            for (int j = 0; j < 4; j++)
                acc[i][j] = __builtin_amdgcn_mfma_f32_16x16x32_bf16(af[i], bfr[j],
                                                                   acc[i][j], 0, 0, 0);
        __syncthreads();
    }
    const float scale = (z == 0) ? 0.0883883476483184f : 1.0f;
    u16* out = (z == 0) ? qb : (z == 1 ? kb : vbT);
#pragma unroll
    for (int i = 0; i < 4; i++) {
        int grow = row0 + wm * 64 + i * 16 + quad * 4;
#pragma unroll
        for (int j = 0; j < 4; j++) {
            int gcol = col0 + wn * 64 + j * 16 + l16;
            int h = gcol >> 7, d = gcol & 127;
#pragma unroll
            for (int r = 0; r < 4; r++) {
                int row = grow + r;
                int b = row >> 12, s = row & (S_LEN - 1);
                float val = acc[i][j][r] * scale;
                if (z == 2)
                    out[((size_t)(b * NHEADS + h) * HEAD_DIM + d) * S_LEN + s] = (u16)f2b(val);
                else
                    out[((size_t)(b * NHEADS + h) * S_LEN + s) * HEAD_DIM + d] = (u16)f2b(val);
            }
        }
    }
}

// ---- flash attention, MFMA. 1 block per (bh, 128-row q tile). K-tile=32. ----
__global__ __launch_bounds__(256) void attn_mfma(const u16* qb, const u16* kb,
                                                 const u16* vbT, u16* attnb) {
    __shared__ short Qs[128][136];
    __shared__ short Ks[32][136];
    __shared__ short Vs[128][40]; // [d][key]
    __shared__ short Ps[128][40]; // [row][key]
    const int bid = blockIdx.x;
    const int qt = bid & 31, bh = bid >> 5;
    const int q0 = qt << 7;
    const int qblk = q0 >> 9;
    const int kstart = (qblk == 0) ? 0 : ((qblk - 1) << 9);
    const int kend = (qblk == 7) ? S_LEN : ((qblk + 2) << 9);
    const int tid = threadIdx.x;
    const int lane = tid & 63, wid = tid >> 6;
    const int l16 = lane & 15, quad = lane >> 4;
    const u16* qp = qb + (size_t)bh * S_LEN * HEAD_DIM;
    const u16* kp = kb + (size_t)bh * S_LEN * HEAD_DIM;
    const u16* vp = vbT + (size_t)bh * HEAD_DIM * S_LEN;

    { // Q tile 128x128
        int r = tid >> 1, c0 = (tid & 1) * 64;
        const u16* src = qp + (size_t)(q0 + r) * HEAD_DIM + c0;
#pragma unroll
        for (int i = 0; i < 8; i++)
            *(bf16x8*)&Qs[r][c0 + 8 * i] = *(const bf16x8*)(src + 8 * i);
    }
    __syncthreads();
    bf16x8 qf[2][4]; // hoisted A-frags: rows wid*32+i*16+l16, k = kc*32+quad*8
#pragma unroll
    for (int i = 0; i < 2; i++)
#pragma unroll
        for (int kc = 0; kc < 4; kc++)
            qf[i][kc] = *(const bf16x8*)&Qs[wid * 32 + i * 16 + l16][kc * 32 + quad * 8];

    float m_i[2][4], l_i[2][4];
    f32x4 o[2][8];
#pragma unroll
    for (int i = 0; i < 2; i++)
#pragma unroll
        for (int r = 0; r < 4; r++) { m_i[i][r] = -1e30f; l_i[i][r] = 0.f; }
#pragma unroll
    for (int i = 0; i < 2; i++)
#pragma unroll
        for (int n = 0; n < 8; n++) o[i][n] = (f32x4){0.f, 0.f, 0.f, 0.f};

    for (int kt = kstart; kt < kend; kt += 32) {
        { // stage K: 32 keys x 128 d
            int r = tid >> 3, c0 = (tid & 7) * 16;
            const u16* src = kp + (size_t)(kt + r) * HEAD_DIM + c0;
            *(bf16x8*)&Ks[r][c0] = *(const bf16x8*)src;
            *(bf16x8*)&Ks[r][c0 + 8] = *(const bf16x8*)(src + 8);
        }
        { // stage V: Vs[d][key] from vbT[d][kt+key]
            int d = tid >> 1, c0 = (tid & 1) * 16;
            const u16* src = vp + (size_t)d * S_LEN + kt + c0;
            *(bf16x8*)&Vs[d][c0] = *(const bf16x8*)src;
            *(bf16x8*)&Vs[d][c0 + 8] = *(const bf16x8*)(src + 8);
        }
        __syncthreads();
        // S = Q K^T : per wave 32 rows x 32 keys
        f32x4 sa[2][2];
#pragma unroll
        for (int i = 0; i < 2; i++)
#pragma unroll
            for (int n = 0; n < 2; n++) sa[i][n] = (f32x4){0.f, 0.f, 0.f, 0.f};
#pragma unroll
        for (int kc = 0; kc < 4; kc++) {
            bf16x8 kf0 = *(const bf16x8*)&Ks[l16][kc * 32 + quad * 8];
            bf16x8 kf1 = *(const bf16x8*)&Ks[16 + l16][kc * 32 + quad * 8];
#pragma unroll
            for (int i = 0; i < 2; i++) {
                sa[i][0] = __builtin_amdgcn_mfma_f32_16x16x32_bf16(qf[i][kc], kf0, sa[i][0], 0, 0, 0);
                sa[i][1] = __builtin_amdgcn_mfma_f32_16x16x32_bf16(qf[i][kc], kf1, sa[i][1], 0, 0, 0);
            }
        }
        // online softmax in C-layout (row = quad*4+r, col = l16 / l16+16)
#pragma unroll
        for (int i = 0; i < 2; i++) {
#pragma unroll
            for (int r = 0; r < 4; r++) {
                float s0 = sa[i][0][r], s1 = sa[i][1][r];
                float mloc = fmaxf(s0, s1);
#pragma unroll
                for (int off = 1; off < 16; off <<= 1)
                    mloc = fmaxf(mloc, __shfl_xor(mloc, off));
                float mnew = fmaxf(m_i[i][r], mloc);
                float alpha = __expf(m_i[i][r] - mnew);
                float p0 = __expf(s0 - mnew);
                float p1 = __expf(s1 - mnew);
                float rs = p0 + p1;
#pragma unroll
                for (int off = 1; off < 16; off <<= 1) rs += __shfl_xor(rs, off);
                l_i[i][r] = l_i[i][r] * alpha + rs;
                m_i[i][r] = mnew;
#pragma unroll
                for (int n = 0; n < 8; n++) o[i][n][r] *= alpha;
                int prow = wid * 32 + i * 16 + quad * 4 + r;
                Ps[prow][l16] = f2b(p0);
                Ps[prow][16 + l16] = f2b(p1);
            }
        }
        __syncthreads();
        // O += P V : P A-frag (rows wid*32+i*16+l16, k=key), V B-frag (n=d, k=key)
        bf16x8 pf[2];
#pragma unroll
        for (int i = 0; i < 2; i++)
            pf[i] = *(const bf16x8*)&Ps[wid * 32 + i * 16 + l16][quad * 8];
#pragma unroll
        for (int n = 0; n < 8; n++) {
            bf16x8 vf = *(const bf16x8*)&Vs[n * 16 + l16][quad * 8];
#pragma unroll
            for (int i = 0; i < 2; i++)
                o[i][n] = __builtin_amdgcn_mfma_f32_16x16x32_bf16(pf[i], vf, o[i][n], 0, 0, 0);
        }
        __syncthreads();
    }
    const int b = bh >> 2, h = bh & 3;
#pragma unroll
    for (int i = 0; i < 2; i++) {
#pragma unroll
        for (int r = 0; r < 4; r++) {
            int row = wid * 32 + i * 16 + quad * 4 + r;
            int s = q0 + row;
            float inv = 1.0f / l_i[i][r];
#pragma unroll
            for (int n = 0; n < 8; n++) {
                int d = n * 16 + l16;
                attnb[((size_t)(b * S_LEN + s)) * D_MODEL + h * HEAD_DIM + d] =
                    (u16)f2b(o[i][n][r] * inv);
            }
        }
    }
}

// ---- output projection: d_out = attnb @ Wo + bo, fp32 out ----
__global__ __launch_bounds__(256) void outproj_mfma(const u16* A, const u16* Wt,
                                                    const void* bias, float* out,
                                                    const int* flags) {
    __shared__ short As[128][40];
    __shared__ short Ws[128][40];
    const int f32b = flags[6];
    const int row0 = blockIdx.x * 128, col0 = blockIdx.y * 128;
    const int tid = threadIdx.x;
    const int srow = tid >> 1, skh = (tid & 1) << 4;
    const int lane = tid & 63, wid = tid >> 6;
    const int wm = wid >> 1, wn = wid & 1;
    const int l16 = lane & 15, quad = lane >> 4;
    f32x4 acc[4][4];
#pragma unroll
    for (int i = 0; i < 4; i++)
#pragma unroll
        for (int j = 0; j < 4; j++) acc[i][j] = (f32x4){0.f, 0.f, 0.f, 0.f};

    for (int k0 = 0; k0 < D_MODEL; k0 += 32) {
        {
            const u16* ap = A + (size_t)(row0 + srow) * D_MODEL + k0 + skh;
            *(bf16x8*)&As[srow][skh] = *(const bf16x8*)ap;
            *(bf16x8*)&As[srow][skh + 8] = *(const bf16x8*)(ap + 8);
            const u16* wp = Wt + (size_t)(col0 + srow) * D_MODEL + k0 + skh;
            *(bf16x8*)&Ws[srow][skh] = *(const bf16x8*)wp;
            *(bf16x8*)&Ws[srow][skh + 8] = *(const bf16x8*)(wp + 8);
        }
        __syncthreads();
        bf16x8 af[4], bfr[4];
#pragma unroll
        for (int i = 0; i < 4; i++)
            af[i] = *(const bf16x8*)&As[wm * 64 + i * 16 + l16][quad * 8];
#pragma unroll
        for (int j = 0; j < 4; j++)
            bfr[j] = *(const bf16x8*)&Ws[wn * 64 + j * 16 + l16][quad * 8];
#pragma unroll
        for (int i = 0; i < 4; i++)
#pragma unroll
            for (int j = 0; j < 4; j++)
                acc[i][j] = __builtin_amdgcn_mfma_f32_16x16x32_bf16(af[i], bfr[j],
                                                                   acc[i][j], 0, 0, 0);
        __syncthreads();
    }
#pragma unroll
    for (int i = 0; i < 4; i++) {
        int grow = row0 + wm * 64 + i * 16 + quad * 4;
#pragma unroll
        for (int j = 0; j < 4; j++) {
            int gcol = col0 + wn * 64 + j * 16 + l16;
            float bval = load_elem(bias, gcol, f32b);
#pragma unroll
            for (int r = 0; r < 4; r++)
                out[(size_t)(grow + r) * D_MODEL + gcol] = acc[i][j][r] + bval;
        }
    }
}

extern "C" void kernel_launch(void* const* d_in, const int* in_sizes, int n_in,
                              void* d_out, int out_size, void* d_ws, size_t ws_size,
                              hipStream_t stream) {
    (void)out_size; (void)ws_size; (void)n_in;
    const void* q_input = d_in[0];
    const void* kv_input = d_in[1];
    const void* Wq = d_in[2];
    const void* Wk = d_in[3];
    const void* Wv = d_in[4];
    const void* Wo = d_in[5];
    const void* bo = d_in[6];
    // d_in[7] = mask: tri-block-diagonal, BLK=512, handled analytically.

    int* flags = (int*)d_ws;
    u16* wt = (u16*)((char*)d_ws + 256);      // 4 x 512x512 bf16 = 2 MiB
    u16* qb = wt + 4 * 262144;                // [bh][s][d]  8 MiB
    u16* kb = qb + 4194304;                   // [bh][s][d]  8 MiB
    u16* vbT = kb + 4194304;                  // [bh][d][s]  8 MiB
    u16* attnb = vbT + 4194304;               // [row][col]  8 MiB
    // total ~34 MiB

    detect_kernel<<<7, 256, 0, stream>>>(q_input, kv_input, Wq, Wk, Wv, Wo, bo,
                                         in_sizes[0], in_sizes[1], in_sizes[2],
                                         in_sizes[3], in_sizes[4], in_sizes[5],
                                         in_sizes[6], flags);
    prep_weights<<<dim3(16, 16, 4), 256, 0, stream>>>(Wq, Wk, Wv, Wo, wt, flags);
    proj_mfma<<<dim3(64, 4, 3), 256, 0, stream>>>(q_input, kv_input, wt, qb, kb, vbT, flags);
    attn_mfma<<<256, 256, 0, stream>>>(qb, kb, vbT, attnb);
    outproj_mfma<<<dim3(64, 4), 256, 0, stream>>>(attnb, wt + 3 * 262144, bo,
                                                  (float*)d_out, flags);
}

// Round 6
// 257.975 us; speedup vs baseline: 15.7575x; 1.1426x over previous
//
#include <hip/hip_runtime.h>
#include <hip/hip_bf16.h>

#define S_LEN 4096
#define D_MODEL 512
#define NHEADS 4
#define HEAD_DIM 128
#define BATCH 2
#define M_ROWS 8192

typedef unsigned short u16;
typedef __attribute__((ext_vector_type(8))) short bf16x8;
typedef __attribute__((ext_vector_type(4))) float f32x4;

__device__ __forceinline__ float bf2f(u16 u) {
    return __uint_as_float(((unsigned)u) << 16);
}
__device__ __forceinline__ short f2b(float f) { // RNE f32->bf16
    unsigned x = __float_as_uint(f);
    unsigned r = (x + 0x7fffu + ((x >> 16) & 1u)) >> 16;
    return (short)r;
}
__device__ __forceinline__ float load_elem(const void* p, long long idx, int f32) {
    if (f32) return ((const float*)p)[idx];
    return bf2f(((const u16*)p)[idx]);
}

// ---- per-tensor dtype detection ----
__global__ __launch_bounds__(256) void detect_kernel(
    const void* a0, const void* a1, const void* a2, const void* a3,
    const void* a4, const void* a5, const void* a6,
    int n0, int n1, int n2, int n3, int n4, int n5, int n6, int* flags) {
    const void* p = a0;
    int n = n0;
    switch (blockIdx.x) {
        case 0: p = a0; n = n0; break;
        case 1: p = a1; n = n1; break;
        case 2: p = a2; n = n2; break;
        case 3: p = a3; n = n3; break;
        case 4: p = a4; n = n4; break;
        case 5: p = a5; n = n5; break;
        case 6: p = a6; n = n6; break;
    }
    __shared__ int s_cnt;
    if (threadIdx.x == 0) s_cnt = 0;
    __syncthreads();
    int samp = n < 4096 ? n : 4096;
    const u16* u = (const u16*)p;
    int cnt = 0;
    for (int i = threadIdx.x; i < samp; i += 256) {
        float f = bf2f(u[i]);
        float af = fabsf(f);
        if (af != 0.0f && (!(af <= 1e12f) || af < 1e-12f)) cnt++;
    }
    atomicAdd(&s_cnt, cnt);
    __syncthreads();
    if (threadIdx.x == 0) flags[blockIdx.x] = (s_cnt > 16) ? 1 : 0;
}

// ---- weights: W[k][n] (f32|bf16) -> Wt[n][k] bf16, 4 matrices ----
__global__ __launch_bounds__(256) void prep_weights(const void* w0, const void* w1,
                                                    const void* w2, const void* w3,
                                                    u16* wt, const int* flags) {
    const void* W;
    int f32;
    switch (blockIdx.z) {
        case 0: W = w0; f32 = flags[2]; break;
        case 1: W = w1; f32 = flags[3]; break;
        case 2: W = w2; f32 = flags[4]; break;
        default: W = w3; f32 = flags[5]; break;
    }
    u16* Wt = wt + (size_t)blockIdx.z * D_MODEL * D_MODEL;
    __shared__ float tile[32][33];
    const int k0 = blockIdx.x * 32, n0 = blockIdx.y * 32;
    const int tx = threadIdx.x & 31, ty = threadIdx.x >> 5;
#pragma unroll
    for (int i = 0; i < 4; i++) {
        int r = ty + 8 * i;
        tile[r][tx] = load_elem(W, (long long)(k0 + r) * D_MODEL + n0 + tx, f32);
    }
    __syncthreads();
#pragma unroll
    for (int i = 0; i < 4; i++) {
        int r = ty + 8 * i;
        Wt[(size_t)(n0 + r) * D_MODEL + k0 + tx] = (u16)f2b(tile[tx][r]);
    }
}

// ---- QKV projection (unchanged from round 5) ----
__global__ __launch_bounds__(256) void proj_mfma(const void* qin, const void* kvin,
                                                 const u16* wt, u16* qb, u16* kb,
                                                 u16* vbT, const int* flags) {
    __shared__ short As[128][40];
    __shared__ short Ws[128][40];
    const int z = blockIdx.z;
    const void* A;
    int f32a;
    const u16* Wt;
    if (z == 0) { A = qin; f32a = flags[0]; Wt = wt; }
    else if (z == 1) { A = kvin; f32a = flags[1]; Wt = wt + 262144; }
    else { A = kvin; f32a = flags[1]; Wt = wt + 2 * 262144; }
    const int row0 = blockIdx.x * 128, col0 = blockIdx.y * 128;
    const int tid = threadIdx.x;
    const int srow = tid >> 1, skh = (tid & 1) << 4;
    const int lane = tid & 63, wid = tid >> 6;
    const int wm = wid >> 1, wn = wid & 1;
    const int l16 = lane & 15, quad = lane >> 4;

    f32x4 acc[4][4];
#pragma unroll
    for (int i = 0; i < 4; i++)
#pragma unroll
        for (int j = 0; j < 4; j++) acc[i][j] = (f32x4){0.f, 0.f, 0.f, 0.f};

    for (int k0 = 0; k0 < D_MODEL; k0 += 32) {
        if (f32a) {
            const float* ap = (const float*)A + (size_t)(row0 + srow) * D_MODEL + k0 + skh;
            short s[16];
#pragma unroll
            for (int i = 0; i < 4; i++) {
                f32x4 t = *(const f32x4*)(ap + 4 * i);
                s[4 * i] = f2b(t.x); s[4 * i + 1] = f2b(t.y);
                s[4 * i + 2] = f2b(t.z); s[4 * i + 3] = f2b(t.w);
            }
            *(bf16x8*)&As[srow][skh] = *(bf16x8*)s;
            *(bf16x8*)&As[srow][skh + 8] = *(bf16x8*)(s + 8);
        } else {
            const u16* ap = (const u16*)A + (size_t)(row0 + srow) * D_MODEL + k0 + skh;
            *(bf16x8*)&As[srow][skh] = *(const bf16x8*)ap;
            *(bf16x8*)&As[srow][skh + 8] = *(const bf16x8*)(ap + 8);
        }
        {
            const u16* wp = Wt + (size_t)(col0 + srow) * D_MODEL + k0 + skh;
            *(bf16x8*)&Ws[srow][skh] = *(const bf16x8*)wp;
            *(bf16x8*)&Ws[srow][skh + 8] = *(const bf16x8*)(wp + 8);
        }
        __syncthreads();
        bf16x8 af[4], bfr[4];
#pragma unroll
        for (int i = 0; i < 4; i++)
            af[i] = *(const bf16x8*)&As[wm * 64 + i * 16 + l16][quad * 8];
#pragma unroll
        for (int j = 0; j < 4; j++)
            bfr[j] = *(const bf16x8*)&Ws[wn * 64 + j * 16 + l16][quad * 8];
#pragma unroll
        for (int i = 0; i < 4; i++)
#pragma unroll
            for (int j = 0; j < 4; j++)
                acc[i][j] = __builtin_amdgcn_mfma_f32_16x16x32_bf16(af[i], bfr[j],
                                                                   acc[i][j], 0, 0, 0);
        __syncthreads();
    }
    const float scale = (z == 0) ? 0.0883883476483184f : 1.0f;
    u16* out = (z == 0) ? qb : (z == 1 ? kb : vbT);
#pragma unroll
    for (int i = 0; i < 4; i++) {
        int grow = row0 + wm * 64 + i * 16 + quad * 4;
#pragma unroll
        for (int j = 0; j < 4; j++) {
            int gcol = col0 + wn * 64 + j * 16 + l16;
            int h = gcol >> 7, d = gcol & 127;
#pragma unroll
            for (int r = 0; r < 4; r++) {
                int row = grow + r;
                int b = row >> 12, s = row & (S_LEN - 1);
                float val = acc[i][j][r] * scale;
                if (z == 2)
                    out[((size_t)(b * NHEADS + h) * HEAD_DIM + d) * S_LEN + s] = (u16)f2b(val);
                else
                    out[((size_t)(b * NHEADS + h) * S_LEN + s) * HEAD_DIM + d] = (u16)f2b(val);
            }
        }
    }
}

// ---- flash attention, MFMA. BQ=64 (4 waves x 16 rows), BK=64. ----
// Grid 512; bh = bid & 7 so each bh's q-tiles stay on one XCD (L2-resident K/V).
__global__ __launch_bounds__(256) void attn_mfma(const u16* qb, const u16* kb,
                                                 const u16* vbT, u16* attnb) {
    __shared__ short Qs[64][136];  // 17.4 KB, stride 272 B (17x16B)
    __shared__ short Ks[64][136];  // 17.4 KB
    __shared__ short Vs[128][72];  // 18.4 KB, [d][key], stride 144 B (9x16B)
    __shared__ short Ps[64][72];   //  9.2 KB
    const int bid = blockIdx.x;
    const int bh = bid & 7, qt = bid >> 3;
    const int q0 = qt << 6;
    const int qblk = q0 >> 9;
    const int kstart = (qblk == 0) ? 0 : ((qblk - 1) << 9);
    const int kend = (qblk == 7) ? S_LEN : ((qblk + 2) << 9);
    const int tid = threadIdx.x;
    const int lane = tid & 63, wid = tid >> 6;
    const int l16 = lane & 15, quad = lane >> 4;
    const u16* qp = qb + (size_t)bh * S_LEN * HEAD_DIM;
    const u16* kp = kb + (size_t)bh * S_LEN * HEAD_DIM;
    const u16* vp = vbT + (size_t)bh * HEAD_DIM * S_LEN;

    { // stage Q 64x128
        int r = tid >> 2, c0 = (tid & 3) * 32;
        const u16* src = qp + (size_t)(q0 + r) * HEAD_DIM + c0;
#pragma unroll
        for (int i = 0; i < 4; i++)
            *(bf16x8*)&Qs[r][c0 + 8 * i] = *(const bf16x8*)(src + 8 * i);
    }
    __syncthreads();
    bf16x8 qf[4]; // wave's 16 rows, k = kc*32 + quad*8
#pragma unroll
    for (int kc = 0; kc < 4; kc++)
        qf[kc] = *(const bf16x8*)&Qs[wid * 16 + l16][kc * 32 + quad * 8];

    float m_i[4], l_i[4];
    f32x4 o[8];
#pragma unroll
    for (int r = 0; r < 4; r++) { m_i[r] = -1e30f; l_i[r] = 0.f; }
#pragma unroll
    for (int n = 0; n < 8; n++) o[n] = (f32x4){0.f, 0.f, 0.f, 0.f};

    for (int kt = kstart; kt < kend; kt += 64) {
        { // stage K: 64 keys x 128 d
            int r = tid >> 2, c0 = (tid & 3) * 32;
            const u16* src = kp + (size_t)(kt + r) * HEAD_DIM + c0;
#pragma unroll
            for (int i = 0; i < 4; i++)
                *(bf16x8*)&Ks[r][c0 + 8 * i] = *(const bf16x8*)(src + 8 * i);
        }
        { // stage V: Vs[d][key] from vbT[d][kt+key]
            int d = tid >> 1, c0 = (tid & 1) * 32;
            const u16* src = vp + (size_t)d * S_LEN + kt + c0;
#pragma unroll
            for (int i = 0; i < 4; i++)
                *(bf16x8*)&Vs[d][c0 + 8 * i] = *(const bf16x8*)(src + 8 * i);
        }
        __syncthreads();
        // S = Q K^T : 16 rows x 64 keys per wave
        f32x4 sa[4];
#pragma unroll
        for (int n = 0; n < 4; n++) sa[n] = (f32x4){0.f, 0.f, 0.f, 0.f};
#pragma unroll
        for (int kc = 0; kc < 4; kc++) {
#pragma unroll
            for (int n = 0; n < 4; n++) {
                bf16x8 kf = *(const bf16x8*)&Ks[n * 16 + l16][kc * 32 + quad * 8];
                sa[n] = __builtin_amdgcn_mfma_f32_16x16x32_bf16(qf[kc], kf, sa[n], 0, 0, 0);
            }
        }
        // online softmax: lane holds rows quad*4+r, cols n*16+l16
#pragma unroll
        for (int r = 0; r < 4; r++) {
            float s0 = sa[0][r], s1 = sa[1][r], s2 = sa[2][r], s3 = sa[3][r];
            float mloc = fmaxf(fmaxf(s0, s1), fmaxf(s2, s3));
#pragma unroll
            for (int off = 1; off < 16; off <<= 1)
                mloc = fmaxf(mloc, __shfl_xor(mloc, off));
            float mnew = fmaxf(m_i[r], mloc);
            float alpha = __expf(m_i[r] - mnew);
            float p0 = __expf(s0 - mnew);
            float p1 = __expf(s1 - mnew);
            float p2 = __expf(s2 - mnew);
            float p3 = __expf(s3 - mnew);
            float rs = (p0 + p1) + (p2 + p3);
#pragma unroll
            for (int off = 1; off < 16; off <<= 1) rs += __shfl_xor(rs, off);
            l_i[r] = l_i[r] * alpha + rs;
            m_i[r] = mnew;
#pragma unroll
            for (int n = 0; n < 8; n++) o[n][r] *= alpha;
            int prow = wid * 16 + quad * 4 + r;
            Ps[prow][l16] = f2b(p0);
            Ps[prow][16 + l16] = f2b(p1);
            Ps[prow][32 + l16] = f2b(p2);
            Ps[prow][48 + l16] = f2b(p3);
        }
        __syncthreads();
        // O += P V
        bf16x8 pf[2];
#pragma unroll
        for (int kc2 = 0; kc2 < 2; kc2++)
            pf[kc2] = *(const bf16x8*)&Ps[wid * 16 + l16][kc2 * 32 + quad * 8];
#pragma unroll
        for (int n = 0; n < 8; n++) {
#pragma unroll
            for (int kc2 = 0; kc2 < 2; kc2++) {
                bf16x8 vf = *(const bf16x8*)&Vs[n * 16 + l16][kc2 * 32 + quad * 8];
                o[n] = __builtin_amdgcn_mfma_f32_16x16x32_bf16(pf[kc2], vf, o[n], 0, 0, 0);
            }
        }
        __syncthreads();
    }
    const int b = bh >> 2, h = bh & 3;
#pragma unroll
    for (int r = 0; r < 4; r++) {
        int s = q0 + wid * 16 + quad * 4 + r;
        float inv = 1.0f / l_i[r];
#pragma unroll
        for (int n = 0; n < 8; n++) {
            int d = n * 16 + l16;
            attnb[((size_t)(b * S_LEN + s)) * D_MODEL + h * HEAD_DIM + d] =
                (u16)f2b(o[n][r] * inv);
        }
    }
}

// ---- output projection: d_out = attnb @ Wo + bo, fp32 out ----
__global__ __launch_bounds__(256) void outproj_mfma(const u16* A, const u16* Wt,
                                                    const void* bias, float* out,
                                                    const int* flags) {
    __shared__ short As[128][40];
    __shared__ short Ws[128][40];
    const int f32b = flags[6];
    const int row0 = blockIdx.x * 128, col0 = blockIdx.y * 128;
    const int tid = threadIdx.x;
    const int srow = tid >> 1, skh = (tid & 1) << 4;
    const int lane = tid & 63, wid = tid >> 6;
    const int wm = wid >> 1, wn = wid & 1;
    const int l16 = lane & 15, quad = lane >> 4;
    f32x4 acc[4][4];
#pragma unroll
    for (int i = 0; i < 4; i++)
#pragma unroll
        for (int j = 0; j < 4; j++) acc[i][j] = (f32x4){0.f, 0.f, 0.f, 0.f};

    for (int k0 = 0; k0 < D_MODEL; k0 += 32) {
        {
            const u16* ap = A + (size_t)(row0 + srow) * D_MODEL + k0 + skh;
            *(bf16x8*)&As[srow][skh] = *(const bf16x8*)ap;
            *(bf16x8*)&As[srow][skh + 8] = *(const bf16x8*)(ap + 8);
            const u16* wp = Wt + (size_t)(col0 + srow) * D_MODEL + k0 + skh;
            *(bf16x8*)&Ws[srow][skh] = *(const bf16x8*)wp;
            *(bf16x8*)&Ws[srow][skh + 8] = *(const bf16x8*)(wp + 8);
        }
        __syncthreads();
        bf16x8 af[4], bfr[4];
#pragma unroll
        for (int i = 0; i < 4; i++)
            af[i] = *(const bf16x8*)&As[wm * 64 + i * 16 + l16][quad * 8];
#pragma unroll
        for (int j = 0; j < 4; j++)
            bfr[j] = *(const bf16x8*)&Ws[wn * 64 + j * 16 + l16][quad * 8];
#pragma unroll
        for (int i = 0; i < 4; i++)
#pragma unroll
            for (int j = 0; j < 4; j++)
                acc[i][j] = __builtin_amdgcn_mfma_f32_16x16x32_bf16(af[i], bfr[j],
                                                                   acc[i][j], 0, 0, 0);
        __syncthreads();
    }
#pragma unroll
    for (int i = 0; i < 4; i++) {
        int grow = row0 + wm * 64 + i * 16 + quad * 4;
#pragma unroll
        for (int j = 0; j < 4; j++) {
            int gcol = col0 + wn * 64 + j * 16 + l16;
            float bval = load_elem(bias, gcol, f32b);
#pragma unroll
            for (int r = 0; r < 4; r++)
                out[(size_t)(grow + r) * D_MODEL + gcol] = acc[i][j][r] + bval;
        }
    }
}

extern "C" void kernel_launch(void* const* d_in, const int* in_sizes, int n_in,
                              void* d_out, int out_size, void* d_ws, size_t ws_size,
                              hipStream_t stream) {
    (void)out_size; (void)ws_size; (void)n_in;
    const void* q_input = d_in[0];
    const void* kv_input = d_in[1];
    const void* Wq = d_in[2];
    const void* Wk = d_in[3];
    const void* Wv = d_in[4];
    const void* Wo = d_in[5];
    const void* bo = d_in[6];
    // d_in[7] = mask: tri-block-diagonal, BLK=512, handled analytically.

    int* flags = (int*)d_ws;
    u16* wt = (u16*)((char*)d_ws + 256);      // 4 x 512x512 bf16 = 2 MiB
    u16* qb = wt + 4 * 262144;                // [bh][s][d]  8 MiB
    u16* kb = qb + 4194304;                   // [bh][s][d]  8 MiB
    u16* vbT = kb + 4194304;                  // [bh][d][s]  8 MiB
    u16* attnb = vbT + 4194304;               // [row][col]  8 MiB

    detect_kernel<<<7, 256, 0, stream>>>(q_input, kv_input, Wq, Wk, Wv, Wo, bo,
                                         in_sizes[0], in_sizes[1], in_sizes[2],
                                         in_sizes[3], in_sizes[4], in_sizes[5],
                                         in_sizes[6], flags);
    prep_weights<<<dim3(16, 16, 4), 256, 0, stream>>>(Wq, Wk, Wv, Wo, wt, flags);
    proj_mfma<<<dim3(64, 4, 3), 256, 0, stream>>>(q_input, kv_input, wt, qb, kb, vbT, flags);
    attn_mfma<<<512, 256, 0, stream>>>(qb, kb, vbT, attnb);
    outproj_mfma<<<dim3(64, 4), 256, 0, stream>>>(attnb, wt + 3 * 262144, bo,
                                                  (float*)d_out, flags);
}